// Round 7
// baseline (600.214 us; speedup 1.0000x reference)
//
#include <hip/hip_runtime.h>
#include <hip/hip_cooperative_groups.h>

namespace cg = cooperative_groups;

#define F 128

typedef short bf16x8 __attribute__((ext_vector_type(8)));   // 8 bf16 = 4 VGPRs
typedef float f32x4  __attribute__((ext_vector_type(4)));

__device__ __forceinline__ unsigned short f2bf(float f) {
    unsigned int u = __float_as_uint(f);
    u += 0x7fffu + ((u >> 16) & 1u);        // round-to-nearest-even
    return (unsigned short)(u >> 16);
}
__device__ __forceinline__ float bf2f(unsigned short s) {
    return __uint_as_float(((unsigned int)s) << 16);
}

// ================= phase device functions (shared by mega + fallback) =================

__device__ void phase_init(const float* __restrict__ x, unsigned short* __restrict__ xh,
                           const float* __restrict__ Ws, const float* __restrict__ Wn,
                           unsigned short* __restrict__ Bpack, int* __restrict__ counts,
                           int n, int gid, int gstride) {
    for (int i = gid; i < n; i += gstride) counts[i] = 0;

    for (int idx = gid; idx < 32768; idx += gstride) {  // B-fragment pack of [Ws;Wn]
        int j    = idx & 7;
        int lane = (idx >> 3) & 63;
        int tile = idx >> 9;
        int s = tile >> 3;
        int t = tile & 7;
        int k = s * 32 + (lane >> 4) * 8 + j;
        int c = t * 16 + (lane & 15);
        float v = (k < F) ? Ws[k * F + c] : Wn[(k - F) * F + c];
        Bpack[idx] = f2bf(v);
    }

    for (int idx = gid; idx < n * 16; idx += gstride) {  // convert 8 floats -> bf16x8
        int node = idx >> 4;
        int c = (idx & 15) * 8;
        const float4* p = (const float4*)(x + (size_t)node * F + c);
        float4 v0 = p[0], v1 = p[1];
        bf16x8 o;
        o[0] = (short)f2bf(v0.x); o[1] = (short)f2bf(v0.y);
        o[2] = (short)f2bf(v0.z); o[3] = (short)f2bf(v0.w);
        o[4] = (short)f2bf(v1.x); o[5] = (short)f2bf(v1.y);
        o[6] = (short)f2bf(v1.z); o[7] = (short)f2bf(v1.w);
        *(bf16x8*)(xh + (size_t)node * F + c) = o;
    }
}

__device__ void phase_hist(const int* __restrict__ dst, int* __restrict__ counts,
                           int E, int gid, int gstride) {
    for (int e = gid; e < E; e += gstride) atomicAdd(&counts[dst[e]], 1);
}

__device__ void phase_scan_local(const int* __restrict__ counts, int* __restrict__ offsets,
                                 int* __restrict__ bsums, int n, int bid, int tid) {
    __shared__ int wsum[4];
    int base = bid * 1024 + tid * 4;
    int4 c = make_int4(0, 0, 0, 0);
    if (base + 3 < n) c = *(const int4*)(counts + base);
    else if (base < n) {
        c.x = counts[base];
        if (base + 1 < n) c.y = counts[base + 1];
        if (base + 2 < n) c.z = counts[base + 2];
    }
    int tsum = c.x + c.y + c.z + c.w;
    int lane = tid & 63, wid = tid >> 6;
    int v = tsum;
    #pragma unroll
    for (int off = 1; off < 64; off <<= 1) {
        int t = __shfl_up(v, off);
        if (lane >= off) v += t;
    }
    if (lane == 63) wsum[wid] = v;
    __syncthreads();
    int wexcl = 0;
    #pragma unroll
    for (int w = 0; w < 3; ++w) if (w < wid) wexcl += wsum[w];
    int texcl = wexcl + v - tsum;
    int4 o;
    o.x = texcl;
    o.y = o.x + c.x;
    o.z = o.y + c.y;
    o.w = o.z + c.z;
    if (base + 3 < n) *(int4*)(offsets + base) = o;
    else if (base < n) {
        offsets[base] = o.x;
        if (base + 1 < n) offsets[base + 1] = o.y;
        if (base + 2 < n) offsets[base + 2] = o.z;
    }
    if (tid == 255) bsums[bid] = wexcl + v;    // raw block total
}

__device__ void phase_scan_add(int* __restrict__ offsets, const int* __restrict__ bsums,
                               int* __restrict__ cursor, int n, int nb, int bid, int tid) {
    __shared__ int boff_s, total_s;
    if (tid < 64) {
        int orig = (tid < nb) ? bsums[tid] : 0;
        int v = orig;
        #pragma unroll
        for (int off = 1; off < 64; off <<= 1) {
            int t = __shfl_up(v, off);
            if ((tid & 63) >= off) v += t;
        }
        if (tid == 63) total_s = v;
        if (tid == bid) boff_s = v - orig;     // exclusive prefix for this block
    }
    __syncthreads();
    int boff = boff_s;
    if (bid == 0 && tid == 0) offsets[n] = total_s;   // == E

    int base = (bid * 256 + tid) * 4;
    if (base >= n) return;
    if (base + 3 < n) {
        int4 v = *(const int4*)(offsets + base);
        v.x += boff; v.y += boff; v.z += boff; v.w += boff;
        *(int4*)(offsets + base) = v;
        *(int4*)(cursor + base) = v;
    } else {
        for (int j = 0; j < 4 && base + j < n; ++j) {
            int v = offsets[base + j] + boff;
            offsets[base + j] = v;
            cursor[base + j] = v;
        }
    }
}

__device__ void phase_fill(const int* __restrict__ src, const int* __restrict__ dst,
                           int* __restrict__ cursor, int* __restrict__ esrc,
                           int E, int gid, int gstride) {
    for (int e = gid; e < E; e += gstride) {
        int p = atomicAdd(&cursor[dst[e]], 1);
        esrc[p] = src[e];
    }
}

__device__ void phase_agg(const unsigned short* __restrict__ xh,
                          const int* __restrict__ esrc, const int* __restrict__ offsets,
                          unsigned short* __restrict__ h, int n, int gid, int gstride) {
    int l16 = gid & 15;                        // 16 lanes x bf16x8 = 128 feats
    int vstride = gstride >> 4;
    for (int v = gid >> 4; v < n; v += vstride) {
        int beg = offsets[v];
        int end = offsets[v + 1];
        float acc[8] = {0.f, 0.f, 0.f, 0.f, 0.f, 0.f, 0.f, 0.f};
        for (int j = beg; j < end; ++j) {
            int s = esrc[j];
            bf16x8 xv = *(const bf16x8*)(xh + (size_t)s * F + l16 * 8);
            #pragma unroll
            for (int i = 0; i < 8; ++i) acc[i] += bf2f((unsigned short)xv[i]);
        }
        float r = (end > beg) ? 1.0f / (float)(end - beg) : 0.f;
        bf16x8 o;
        #pragma unroll
        for (int i = 0; i < 8; ++i) o[i] = (short)f2bf(acc[i] * r);
        *(bf16x8*)(h + (size_t)v * F + l16 * 8) = o;
    }
}

__device__ void phase_gemm(const unsigned short* __restrict__ xh,
                           const unsigned short* __restrict__ h,
                           const unsigned short* __restrict__ Bpack,
                           const float* __restrict__ bias,
                           float* __restrict__ out, int n, int tile, int tid) {
    int wave = tid >> 6;
    int lane = tid & 63;
    int q = lane >> 4;
    int m = lane & 15;
    int rowhalf = (wave & 1) * 32;
    int coltile = (wave >> 1) * 4;
    int row0 = tile * 64 + rowhalf;

    f32x4 acc[2][4];
    #pragma unroll
    for (int r = 0; r < 2; ++r)
        #pragma unroll
        for (int t = 0; t < 4; ++t) acc[r][t] = 0.f;

    int r0 = min(row0 + m, n - 1);
    int r1 = min(row0 + 16 + m, n - 1);
    const unsigned short* a0p = xh + (size_t)r0 * F + q * 8;
    const unsigned short* a1p = xh + (size_t)r1 * F + q * 8;
    const unsigned short* h0p = h + (size_t)r0 * F + q * 8;
    const unsigned short* h1p = h + (size_t)r1 * F + q * 8;

    #pragma unroll
    for (int s = 0; s < 8; ++s) {
        bf16x8 a0 = (s < 4) ? *(const bf16x8*)(a0p + s * 32)
                            : *(const bf16x8*)(h0p + (s - 4) * 32);
        bf16x8 a1 = (s < 4) ? *(const bf16x8*)(a1p + s * 32)
                            : *(const bf16x8*)(h1p + (s - 4) * 32);
        #pragma unroll
        for (int t = 0; t < 4; ++t) {
            bf16x8 bf = *(const bf16x8*)(Bpack + ((size_t)((s * 8 + coltile + t) * 64 + lane)) * 8);
            acc[0][t] = __builtin_amdgcn_mfma_f32_16x16x32_bf16(a0, bf, acc[0][t], 0, 0, 0);
            acc[1][t] = __builtin_amdgcn_mfma_f32_16x16x32_bf16(a1, bf, acc[1][t], 0, 0, 0);
        }
    }

    #pragma unroll
    for (int r = 0; r < 2; ++r)
        #pragma unroll
        for (int t = 0; t < 4; ++t) {
            int col = (coltile + t) * 16 + m;
            float bv = bias[col];
            #pragma unroll
            for (int g = 0; g < 4; ++g) {
                int row = row0 + r * 16 + q * 4 + g;
                if (row < n)
                    out[(size_t)row * F + col] = fmaxf(acc[r][t][g] + bv, 0.f);
            }
        }
}

// ================= the cooperative mega-kernel =================

__global__ __launch_bounds__(256, 4) void mega_kernel(
        const float* __restrict__ x, const float* __restrict__ Ws,
        const float* __restrict__ Wn, const float* __restrict__ bias,
        const int* __restrict__ src, const int* __restrict__ dst,
        unsigned short* __restrict__ xh, unsigned short* __restrict__ h,
        unsigned short* __restrict__ Bpack,
        int* __restrict__ counts, int* __restrict__ offsets, int* __restrict__ cursor,
        int* __restrict__ esrc, int* __restrict__ bsums,
        float* __restrict__ out, int n, int E, int nb, int nTiles) {
    cg::grid_group grid = cg::this_grid();
    int tid = threadIdx.x;
    int gid = blockIdx.x * 256 + tid;
    int gstride = gridDim.x * 256;

    phase_init(x, xh, Ws, Wn, Bpack, counts, n, gid, gstride);
    grid.sync();

    phase_hist(dst, counts, E, gid, gstride);
    grid.sync();

    if ((int)blockIdx.x < nb) phase_scan_local(counts, offsets, bsums, n, blockIdx.x, tid);
    grid.sync();

    if ((int)blockIdx.x < nb) phase_scan_add(offsets, bsums, cursor, n, nb, blockIdx.x, tid);
    grid.sync();

    phase_fill(src, dst, cursor, esrc, E, gid, gstride);
    grid.sync();

    phase_agg(xh, esrc, offsets, h, n, gid, gstride);
    grid.sync();

    for (int tile = blockIdx.x; tile < nTiles; tile += gridDim.x)
        phase_gemm(xh, h, Bpack, bias, out, n, tile, tid);
}

// ================= fallback wrappers (regular launches) =================

__global__ __launch_bounds__(256) void k_init(const float* x, unsigned short* xh,
                                              const float* Ws, const float* Wn,
                                              unsigned short* Bpack, int* counts, int n) {
    phase_init(x, xh, Ws, Wn, Bpack, counts, n,
               blockIdx.x * 256 + threadIdx.x, gridDim.x * 256);
}
__global__ __launch_bounds__(256) void k_hist(const int* dst, int* counts, int E) {
    phase_hist(dst, counts, E, blockIdx.x * 256 + threadIdx.x, gridDim.x * 256);
}
__global__ __launch_bounds__(256) void k_scan_local(const int* counts, int* offsets,
                                                    int* bsums, int n) {
    phase_scan_local(counts, offsets, bsums, n, blockIdx.x, threadIdx.x);
}
__global__ __launch_bounds__(256) void k_scan_add(int* offsets, const int* bsums,
                                                  int* cursor, int n, int nb) {
    phase_scan_add(offsets, bsums, cursor, n, nb, blockIdx.x, threadIdx.x);
}
__global__ __launch_bounds__(256) void k_fill(const int* src, const int* dst,
                                              int* cursor, int* esrc, int E) {
    phase_fill(src, dst, cursor, esrc, E, blockIdx.x * 256 + threadIdx.x, gridDim.x * 256);
}
__global__ __launch_bounds__(256) void k_agg(const unsigned short* xh, const int* esrc,
                                             const int* offsets, unsigned short* h, int n) {
    phase_agg(xh, esrc, offsets, h, n, blockIdx.x * 256 + threadIdx.x, gridDim.x * 256);
}
__global__ __launch_bounds__(256) void k_gemm(const unsigned short* xh, const unsigned short* h,
                                              const unsigned short* Bpack, const float* bias,
                                              float* out, int n) {
    phase_gemm(xh, h, Bpack, bias, out, n, blockIdx.x, threadIdx.x);
}

extern "C" void kernel_launch(void* const* d_in, const int* in_sizes, int n_in,
                              void* d_out, int out_size, void* d_ws, size_t ws_size,
                              hipStream_t stream) {
    const float* x  = (const float*)d_in[0];
    const float* Ws = (const float*)d_in[1];
    const float* Wn = (const float*)d_in[2];
    const float* b  = (const float*)d_in[3];
    const int* src  = (const int*)d_in[4];
    const int* dst  = (const int*)d_in[5];
    int n = in_sizes[0] / F;      // 50000
    int E = in_sizes[4];          // 600000

    int nb = (n + 1023) / 1024;   // 49  (<= 64 required by scan_add)
    int nTiles = (n + 63) / 64;   // 782

    // workspace layout (4B elems):
    //   xh      : n*128 bf16   12.8 MB   (x in bf16)
    //   h       : n*128 bf16   12.8 MB   (aggregated means, bf16)
    //   counts  : n ints
    //   offsets : n+1 ints
    //   cursor  : n ints
    //   esrc    : E ints
    //   bsums   : nb ints
    //   Bpack   : 32768 bf16 (64 KB)
    unsigned short* xh = (unsigned short*)d_ws;
    unsigned short* h  = xh + (size_t)n * F;
    int* counts  = (int*)(h + (size_t)n * F);
    int* offsets = counts + n;
    int* cursor  = offsets + (n + 1);
    int* esrc    = cursor + n;
    int* bsums   = esrc + E;
    unsigned short* Bpack = (unsigned short*)(bsums + nb);

    float* out = (float*)d_out;

    // ---- cooperative single-dispatch path ----
    int blocksPerCU = 0;
    hipError_t qerr = hipOccupancyMaxActiveBlocksPerMultiprocessor(
        &blocksPerCU, (const void*)mega_kernel, 256, 0);
    if (qerr != hipSuccess || blocksPerCU < 1) blocksPerCU = 2;
    int gridBlocks = blocksPerCU * 256;          // 256 CUs on MI355X
    if (gridBlocks > 2048) gridBlocks = 2048;

    void* args[] = { (void*)&x, (void*)&Ws, (void*)&Wn, (void*)&b,
                     (void*)&src, (void*)&dst,
                     (void*)&xh, (void*)&h, (void*)&Bpack,
                     (void*)&counts, (void*)&offsets, (void*)&cursor,
                     (void*)&esrc, (void*)&bsums,
                     (void*)&out, (void*)&n, (void*)&E, (void*)&nb, (void*)&nTiles };

    hipError_t lerr = hipLaunchCooperativeKernel(
        (const void*)mega_kernel, dim3(gridBlocks), dim3(256), args, 0, stream);

    if (lerr != hipSuccess) {
        // ---- fallback: same phases as 7 regular dispatches ----
        k_init<<<(n * 16 + 255) / 256, 256, 0, stream>>>(x, xh, Ws, Wn, Bpack, counts, n);
        k_hist<<<(E + 255) / 256, 256, 0, stream>>>(dst, counts, E);
        k_scan_local<<<nb, 256, 0, stream>>>(counts, offsets, bsums, n);
        k_scan_add<<<nb, 256, 0, stream>>>(offsets, bsums, cursor, n, nb);
        k_fill<<<(E + 255) / 256, 256, 0, stream>>>(src, dst, cursor, esrc, E);
        k_agg<<<(n + 15) / 16, 256, 0, stream>>>(xh, esrc, offsets, h, n);
        k_gemm<<<nTiles, 256, 0, stream>>>(xh, h, Bpack, b, out, n);
    }
}

// Round 8
// 190.720 us; speedup vs baseline: 3.1471x; 3.1471x over previous
//
#include <hip/hip_runtime.h>

#define F 128
#define HP 136   // bf16 LDS row stride (272 B)

typedef short bf16x8 __attribute__((ext_vector_type(8)));   // 8 bf16 = 4 VGPRs
typedef float f32x4  __attribute__((ext_vector_type(4)));

__device__ __forceinline__ unsigned short f2bf(float f) {
    unsigned int u = __float_as_uint(f);
    u += 0x7fffu + ((u >> 16) & 1u);        // round-to-nearest-even
    return (unsigned short)(u >> 16);
}
__device__ __forceinline__ float bf2f(unsigned short s) {
    return __uint_as_float(((unsigned int)s) << 16);
}

// ---------------- init: zero counts + convert x->bf16 + pack W ----------------
__global__ __launch_bounds__(256) void init_kernel(const float* __restrict__ x,
                                                   unsigned short* __restrict__ xh,
                                                   const float* __restrict__ Ws,
                                                   const float* __restrict__ Wn,
                                                   unsigned short* __restrict__ Bpack,
                                                   int* __restrict__ counts, int n) {
    int idx = blockIdx.x * 256 + threadIdx.x;

    if (idx < n) counts[idx] = 0;

    if (idx < 32768) {   // B-fragment pack of [Ws;Wn] (256x128)
        int j    = idx & 7;
        int lane = (idx >> 3) & 63;
        int tile = idx >> 9;        // 0..63
        int s = tile >> 3;
        int t = tile & 7;
        int k = s * 32 + (lane >> 4) * 8 + j;
        int c = t * 16 + (lane & 15);
        float v = (k < F) ? Ws[k * F + c] : Wn[(k - F) * F + c];
        Bpack[idx] = f2bf(v);
    }

    if (idx < n * 16) {  // one thread per 8 floats
        int node = idx >> 4;
        int c = (idx & 15) * 8;
        const float4* p = (const float4*)(x + (size_t)node * F + c);
        float4 v0 = p[0], v1 = p[1];
        bf16x8 o;
        o[0] = (short)f2bf(v0.x); o[1] = (short)f2bf(v0.y);
        o[2] = (short)f2bf(v0.z); o[3] = (short)f2bf(v0.w);
        o[4] = (short)f2bf(v1.x); o[5] = (short)f2bf(v1.y);
        o[6] = (short)f2bf(v1.z); o[7] = (short)f2bf(v1.w);
        *(bf16x8*)(xh + (size_t)node * F + c) = o;
    }
}

// ---------------- histogram of dst ----------------
__global__ __launch_bounds__(256) void hist_kernel(const int* __restrict__ dst,
                                                   int* __restrict__ counts, int E) {
    int e = blockIdx.x * blockDim.x + threadIdx.x;
    if (e < E) atomicAdd(&counts[dst[e]], 1);
}

// ---------------- scan phase 1: per-block (1024 elems) scan + raw block sums ----------------
__global__ __launch_bounds__(256) void scan_local_kernel(const int* __restrict__ counts,
                                                         int* __restrict__ offsets,
                                                         int* __restrict__ bsums, int n) {
    __shared__ int wsum[4];
    int tid = threadIdx.x;
    int base = blockIdx.x * 1024 + tid * 4;
    int4 c = make_int4(0, 0, 0, 0);
    if (base + 3 < n) c = *(const int4*)(counts + base);
    else if (base < n) {
        c.x = counts[base];
        if (base + 1 < n) c.y = counts[base + 1];
        if (base + 2 < n) c.z = counts[base + 2];
    }
    int tsum = c.x + c.y + c.z + c.w;
    int lane = tid & 63, wid = tid >> 6;
    int v = tsum;
    #pragma unroll
    for (int off = 1; off < 64; off <<= 1) {
        int t = __shfl_up(v, off);
        if (lane >= off) v += t;
    }
    if (lane == 63) wsum[wid] = v;
    __syncthreads();
    int wexcl = 0;
    #pragma unroll
    for (int w = 0; w < 3; ++w) if (w < wid) wexcl += wsum[w];
    int texcl = wexcl + v - tsum;
    int4 o;
    o.x = texcl;
    o.y = o.x + c.x;
    o.z = o.y + c.y;
    o.w = o.z + c.z;
    if (base + 3 < n) *(int4*)(offsets + base) = o;
    else if (base < n) {
        offsets[base] = o.x;
        if (base + 1 < n) offsets[base + 1] = o.y;
        if (base + 2 < n) offsets[base + 2] = o.z;
    }
    if (tid == 255) bsums[blockIdx.x] = wexcl + v;   // raw block total
}

// ---------------- scan phase 2 (bsums wave-scan folded per block); nb <= 64 ----------------
__global__ __launch_bounds__(256) void scan_add_kernel(int* __restrict__ offsets,
                                                       const int* __restrict__ bsums,
                                                       int* __restrict__ cursor, int n, int nb) {
    __shared__ int boff_s, total_s;
    int tid = threadIdx.x;
    if (tid < 64) {
        int orig = (tid < nb) ? bsums[tid] : 0;
        int v = orig;
        #pragma unroll
        for (int off = 1; off < 64; off <<= 1) {
            int t = __shfl_up(v, off);
            if ((tid & 63) >= off) v += t;
        }
        if (tid == 63) total_s = v;
        if (tid == (int)blockIdx.x) boff_s = v - orig;   // exclusive prefix for this block
    }
    __syncthreads();
    int boff = boff_s;
    if (blockIdx.x == 0 && tid == 0) offsets[n] = total_s;   // == E

    int base = (blockIdx.x * 256 + tid) * 4;
    if (base >= n) return;
    if (base + 3 < n) {
        int4 v = *(const int4*)(offsets + base);
        v.x += boff; v.y += boff; v.z += boff; v.w += boff;
        *(int4*)(offsets + base) = v;
        *(int4*)(cursor + base) = v;
    } else {
        for (int j = 0; j < 4 && base + j < n; ++j) {
            int v = offsets[base + j] + boff;
            offsets[base + j] = v;
            cursor[base + j] = v;
        }
    }
}

// ---------------- fill CSR buckets ----------------
__global__ __launch_bounds__(256) void fill_kernel(const int* __restrict__ src,
                                                   const int* __restrict__ dst,
                                                   int* __restrict__ cursor,
                                                   int* __restrict__ esrc, int E) {
    int e = blockIdx.x * blockDim.x + threadIdx.x;
    if (e < E) {
        int p = atomicAdd(&cursor[dst[e]], 1);
        esrc[p] = src[e];
    }
}

// ---------------- fused aggregate + MFMA GEMM, 16 nodes/block (3125 blocks) ----------------
// Phase A: 16 lanes/node x 16 nodes, all parallel (same shape as R5 standalone agg).
// Phase B: 16-row MFMA tile; x-part A-frags from global, h-part from 4.4 KB LDS.
__global__ __launch_bounds__(256) void agg_gemm_kernel(
        const unsigned short* __restrict__ xh,      // n x 128 bf16
        const int* __restrict__ esrc,
        const int* __restrict__ offsets,
        const unsigned short* __restrict__ Bpack,
        const float* __restrict__ bias,
        float* __restrict__ out, int n) {
    __shared__ __align__(16) unsigned short hs[16 * HP];

    int tid = threadIdx.x;
    int r0 = blockIdx.x * 16;

    // ---- phase A: gather mean ----
    int l16 = tid & 15;
    int g = tid >> 4;              // node 0..15 in tile
    int v = r0 + g;
    float acc[8] = {0.f, 0.f, 0.f, 0.f, 0.f, 0.f, 0.f, 0.f};
    if (v < n) {
        int beg = offsets[v];
        int end = offsets[v + 1];
        for (int j = beg; j < end; ++j) {
            int s = esrc[j];
            bf16x8 xv = *(const bf16x8*)(xh + (size_t)s * F + l16 * 8);
            #pragma unroll
            for (int i = 0; i < 8; ++i) acc[i] += bf2f((unsigned short)xv[i]);
        }
        float r = (end > beg) ? 1.0f / (float)(end - beg) : 0.f;
        #pragma unroll
        for (int i = 0; i < 8; ++i) acc[i] *= r;
    }
    bf16x8 o;
    #pragma unroll
    for (int i = 0; i < 8; ++i) o[i] = (short)f2bf(acc[i]);
    *(bf16x8*)(&hs[g * HP + l16 * 8]) = o;
    __syncthreads();

    // ---- phase B: 4 waves x (16 rows x 32 cols) ----
    int wave = tid >> 6;
    int lane = tid & 63;
    int q = lane >> 4;
    int m = lane & 15;

    f32x4 acc2[2];
    acc2[0] = 0.f; acc2[1] = 0.f;

    int rA = min(r0 + m, n - 1);
    const unsigned short* ap = xh + (size_t)rA * F + q * 8;
    const unsigned short* hp = &hs[m * HP + q * 8];

    #pragma unroll
    for (int s = 0; s < 8; ++s) {
        bf16x8 a = (s < 4) ? *(const bf16x8*)(ap + s * 32)
                           : *(const bf16x8*)(hp + (s - 4) * 32);
        #pragma unroll
        for (int t = 0; t < 2; ++t) {
            bf16x8 bf = *(const bf16x8*)(Bpack + ((size_t)((s * 8 + wave * 2 + t) * 64 + lane)) * 8);
            acc2[t] = __builtin_amdgcn_mfma_f32_16x16x32_bf16(a, bf, acc2[t], 0, 0, 0);
        }
    }

    #pragma unroll
    for (int t = 0; t < 2; ++t) {
        int col = (wave * 2 + t) * 16 + m;
        float bv = bias[col];
        #pragma unroll
        for (int g2 = 0; g2 < 4; ++g2) {
            int row = r0 + q * 4 + g2;
            if (row < n)
                out[(size_t)row * F + col] = fmaxf(acc2[t][g2] + bv, 0.f);
        }
    }
}

extern "C" void kernel_launch(void* const* d_in, const int* in_sizes, int n_in,
                              void* d_out, int out_size, void* d_ws, size_t ws_size,
                              hipStream_t stream) {
    const float* x  = (const float*)d_in[0];
    const float* Ws = (const float*)d_in[1];
    const float* Wn = (const float*)d_in[2];
    const float* b  = (const float*)d_in[3];
    const int* src  = (const int*)d_in[4];
    const int* dst  = (const int*)d_in[5];
    int n = in_sizes[0] / F;      // 50000
    int E = in_sizes[4];          // 600000

    int nb = (n + 1023) / 1024;   // 49 (<= 64 required by scan_add)

    // workspace layout (4B elems):
    //   xh      : n*128 bf16 (x only)     12.8 MB
    //   counts  : n ints
    //   offsets : n+1 ints
    //   cursor  : n ints
    //   esrc    : E ints
    //   bsums   : nb ints
    //   Bpack   : 32768 bf16 (64 KB)
    unsigned short* xh = (unsigned short*)d_ws;
    int* counts  = (int*)(xh + (size_t)n * F);
    int* offsets = counts + n;
    int* cursor  = offsets + (n + 1);
    int* esrc    = cursor + n;
    int* bsums   = esrc + E;
    unsigned short* Bpack = (unsigned short*)(bsums + nb);

    float* out = (float*)d_out;

    init_kernel<<<(n * 16 + 255) / 256, 256, 0, stream>>>(x, xh, Ws, Wn, Bpack, counts, n);
    hist_kernel<<<(E + 255) / 256, 256, 0, stream>>>(dst, counts, E);
    scan_local_kernel<<<nb, 256, 0, stream>>>(counts, offsets, bsums, n);
    scan_add_kernel<<<nb, 256, 0, stream>>>(offsets, bsums, cursor, n, nb);
    fill_kernel<<<(E + 255) / 256, 256, 0, stream>>>(src, dst, cursor, esrc, E);
    agg_gemm_kernel<<<(n + 15) / 16, 256, 0, stream>>>(xh, esrc, offsets, Bpack, b, out, n);
}